// Round 12
// baseline (114.131 us; speedup 1.0000x reference)
//
#include <hip/hip_runtime.h>

// Involution2d, 3-kernel split (R9 components, de-fused).
// K0:  x f32 [b][ch][px] -> xp8 bf16 [b][oct=ch/8][px][8ch]; w -> bf16.
// K1g: LDS-free barrier-free MFMA GEMM (R9's K-loop verbatim);
//      epilogue -> kern_ws bf16 [b][m=784][px] (coalesced stores).
// K2a: apply; kv from 49 coalesced global loads of kern_ws; halo from xp8
//      (b128 copy into 11.2 KB LDS, batch-1 register-prefetched).

#define B_   4
#define C_   256
#define G_   16
#define KK_  49
#define M_   784
#define KS_  7
#define PD_  3

#define KERN_BYTES (B_*M_*4096*2)        // 25,690,112
#define XP8_BYTES  (B_*32*4096*8*2)      //  8,388,608
#define XP8_OFF    KERN_BYTES
#define WBF_OFF    (KERN_BYTES + XP8_BYTES)

#define HC_   70            // halo cols
#define HPOS  (10*HC_)      // 700 positions (10 rows x 70 cols)

typedef __attribute__((ext_vector_type(8))) short bf16x8;
typedef __attribute__((ext_vector_type(4))) float f32x4;
typedef unsigned short ushort_t;

__device__ inline unsigned f2bf(float f) {            // RNE fp32->bf16
    unsigned u = __float_as_uint(f);
    u += 0x7FFF + ((u >> 16) & 1);
    return u >> 16;
}
__device__ inline float bf2f(unsigned short s) {
    return __uint_as_float(((unsigned)s) << 16);
}

// ---------------- K0: x -> xp8 (channel-packed bf16); w -> bf16 ----------------
__global__ __launch_bounds__(256)
void cvt_xp8(const float* __restrict__ x, const float* __restrict__ wk,
             ushort_t* __restrict__ xp8, unsigned* __restrict__ wbf) {
    const int t = threadIdx.x;
    if (blockIdx.x == 64) {   // W convert: 100352 f32 pairs, 16 slices
        const int slice = blockIdx.z * 4 + blockIdx.y;
        const float2* wk2 = (const float2*)wk;
        const int base = slice * 6272;
        for (int k = t; k < 6272; k += 256) {
            float2 v = wk2[base + k];
            wbf[base + k] = f2bf(v.x) | (f2bf(v.y) << 16);
        }
        return;
    }
    __shared__ float tile[64][65];
    const int p0 = blockIdx.x * 64;
    const int c0 = blockIdx.y * 64;       // 8 octs per slice
    const int b  = blockIdx.z;
    const int px_r = t & 63;
    #pragma unroll
    for (int i = 0; i < 16; ++i) {
        int ch = (t >> 6) + i * 4;
        tile[ch][px_r] = x[((size_t)(b * C_ + c0 + ch) << 12) + p0 + px_r];
    }
    __syncthreads();
    const int px = t & 63;
    const int ob = t >> 6;                // 0..3
    #pragma unroll
    for (int jj = 0; jj < 2; ++jj) {
        const int j = ob + jj * 4;        // oct within slice, 0..7
        unsigned u[4];
        #pragma unroll
        for (int k2 = 0; k2 < 4; ++k2) {
            float a0 = tile[j * 8 + 2 * k2][px];
            float a1 = tile[j * 8 + 2 * k2 + 1][px];
            u[k2] = f2bf(a0) | (f2bf(a1) << 16);
        }
        ushort_t* dst = xp8 + (((size_t)((b << 5) + (c0 >> 3) + j) << 12) + p0 + px) * 8;
        *(uint4*)dst = make_uint4(u[0], u[1], u[2], u[3]);
    }
}

// ---------------- K1g: LDS-free barrier-free GEMM -> kern_ws ----------------
__global__ __launch_bounds__(256, 4)
void kern_gemm(const ushort_t* __restrict__ xp8,
               const ushort_t* __restrict__ wbf,
               const float* __restrict__ bk,
               ushort_t* __restrict__ kern) {
    const int bid  = blockIdx.x;
    const int g    = bid >> 6;
    const int b    = (bid >> 4) & 3;
    const int tile = bid & 15;
    const int p0   = tile * 256;

    const int tid  = threadIdx.x;
    const int wv   = tid >> 6;
    const int ln15 = tid & 15;
    const int quad = (tid & 63) >> 4;

    f32x4 acc[16];
    #pragma unroll
    for (int i = 0; i < 16; ++i) acc[i] = (f32x4){0.f, 0.f, 0.f, 0.f};

    const ushort_t* ap[4];
    #pragma unroll
    for (int mt = 0; mt < 4; ++mt) {
        int r = mt * 16 + ln15; if (r > KK_ - 1) r = KK_ - 1;   // clamp pad rows
        ap[mt] = wbf + (size_t)(g * KK_ + r) * C_ + quad * 8;
    }
    const ushort_t* bp = xp8 + (((size_t)((b << 5) + quad) << 12) + p0 + wv * 64 + ln15) * 8;

    bf16x8 af[2][4], bf[2][4];
    #pragma unroll
    for (int mt = 0; mt < 4; ++mt) af[0][mt] = *(const bf16x8*)(ap[mt]);
    #pragma unroll
    for (int nt = 0; nt < 4; ++nt) bf[0][nt] = *(const bf16x8*)(bp + nt * 128);

    #pragma unroll
    for (int k = 0; k < 8; ++k) {
        const int cur = k & 1, nxt = cur ^ 1;
        if (k < 7) {
            const int cc = (k + 1) * 32;
            #pragma unroll
            for (int mt = 0; mt < 4; ++mt)
                af[nxt][mt] = *(const bf16x8*)(ap[mt] + cc);
            #pragma unroll
            for (int nt = 0; nt < 4; ++nt)
                bf[nxt][nt] = *(const bf16x8*)(bp + ((size_t)cc << 12) + nt * 128);
        }
        #pragma unroll
        for (int mt = 0; mt < 4; ++mt) {
            #pragma unroll
            for (int nt = 0; nt < 4; ++nt) {
                acc[mt * 4 + nt] = __builtin_amdgcn_mfma_f32_16x16x32_bf16(
                    af[cur][mt], bf[cur][nt], acc[mt * 4 + nt], 0, 0, 0);
            }
        }
    }

    // epilogue: D[m=quad*4+r][n=ln15] -> kern[b][g*49+m][p0 + wv*64 + nt*16 + ln15]
    const size_t kb0 = ((size_t)(b * M_ + g * KK_) << 12) + p0 + wv * 64 + ln15;
    #pragma unroll
    for (int mt = 0; mt < 3; ++mt) {                      // m <= 47: all valid
        #pragma unroll
        for (int r = 0; r < 4; ++r) {
            const int m = mt * 16 + quad * 4 + r;
            const float bias = bk[g * KK_ + m];
            #pragma unroll
            for (int nt = 0; nt < 4; ++nt) {
                kern[kb0 + ((size_t)m << 12) + nt * 16] =
                    (ushort_t)f2bf(acc[mt * 4 + nt][r] + bias);
            }
        }
    }
    if (quad == 0) {                                      // mt=3: only m=48 valid
        const float b48 = bk[g * KK_ + 48];
        #pragma unroll
        for (int nt = 0; nt < 4; ++nt) {
            kern[kb0 + ((size_t)48 << 12) + nt * 16] =
                (ushort_t)f2bf(acc[12 + nt][0] + b48);
        }
    }
}

// halo position load: one b128 from xp8 (8 channels), zero-padded
__device__ inline uint4 stage_ld(const ushort_t* __restrict__ xp8,
                                 int b, int oct, int gy0, int e) {
    const int row = e / HC_;
    const int col = e - row * HC_;
    const int sy = gy0 + row - PD_;
    const int sx = col - PD_;
    if (sy >= 0 && sy < 64 && sx >= 0 && sx < 64)
        return *(const uint4*)(xp8 + (((size_t)((b << 5) + oct) << 12) + sy * 64 + sx) * 8);
    return make_uint4(0u, 0u, 0u, 0u);
}

// ---------------- K2a: apply ----------------
__global__ __launch_bounds__(256, 5)
void inv_apply(const ushort_t* __restrict__ xp8,
               const ushort_t* __restrict__ kern,
               float* __restrict__ out) {
    __shared__ unsigned halo4[HPOS * 4];      // 11,200 B  [pos][4dw = 8 ch bf16]

    const int bid  = blockIdx.x;
    const int g    = bid >> 6;
    const int b    = (bid >> 4) & 3;
    const int tile = bid & 15;
    const int gy0  = tile * 4;
    const int p0   = tile * 256;

    const int tid = threadIdx.x;

    // 49 kern values for this pixel: coalesced (512 B per instr across block)
    float kv[KK_];
    {
        const ushort_t* kb = kern + ((size_t)(b * M_ + g * KK_) << 12) + p0 + tid;
        #pragma unroll
        for (int j = 0; j < KK_; ++j) kv[j] = bf2f(kb[(size_t)j << 12]);
    }

    // halo batch 0 into LDS
    for (int e = tid; e < HPOS; e += 256)
        *(uint4*)&halo4[e * 4] = stage_ld(xp8, b, 2 * g, gy0, e);
    __syncthreads();

    // prefetch halo batch 1 into registers (in flight during apply0)
    uint4 pf0 = stage_ld(xp8, b, 2 * g + 1, gy0, tid);
    uint4 pf1 = stage_ld(xp8, b, 2 * g + 1, gy0, tid + 256);
    uint4 pf2 = (tid < HPOS - 512) ? stage_ld(xp8, b, 2 * g + 1, gy0, tid + 512)
                                   : make_uint4(0u, 0u, 0u, 0u);

    const int py = tid >> 6, px = tid & 63;

    #pragma unroll 1
    for (int hb = 0; hb < 2; ++hb) {
        if (hb) {
            __syncthreads();   // all done reading halo0
            *(uint4*)&halo4[tid * 4] = pf0;
            *(uint4*)&halo4[(tid + 256) * 4] = pf1;
            if (tid < HPOS - 512) *(uint4*)&halo4[(tid + 512) * 4] = pf2;
            __syncthreads();   // halo1 complete
        }
        float a[8];
        #pragma unroll
        for (int q = 0; q < 8; ++q) a[q] = 0.f;
        #pragma unroll
        for (int kh = 0; kh < KS_; ++kh) {
            const uint4* hr = (const uint4*)&halo4[((py + kh) * HC_ + px) * 4];
            #pragma unroll
            for (int kw = 0; kw < KS_; ++kw) {
                uint4 hv = hr[kw];
                float kk = kv[kh * KS_ + kw];
                a[0] = fmaf(__uint_as_float(hv.x << 16),          kk, a[0]);
                a[1] = fmaf(__uint_as_float(hv.x & 0xffff0000u),  kk, a[1]);
                a[2] = fmaf(__uint_as_float(hv.y << 16),          kk, a[2]);
                a[3] = fmaf(__uint_as_float(hv.y & 0xffff0000u),  kk, a[3]);
                a[4] = fmaf(__uint_as_float(hv.z << 16),          kk, a[4]);
                a[5] = fmaf(__uint_as_float(hv.z & 0xffff0000u),  kk, a[5]);
                a[6] = fmaf(__uint_as_float(hv.w << 16),          kk, a[6]);
                a[7] = fmaf(__uint_as_float(hv.w & 0xffff0000u),  kk, a[7]);
            }
        }
        const size_t o = ((size_t)(b * C_ + g * 16 + hb * 8) << 12) + p0 + tid;
        #pragma unroll
        for (int q = 0; q < 8; ++q)
            out[o + ((size_t)q << 12)] = a[q];
    }
}

extern "C" void kernel_launch(void* const* d_in, const int* in_sizes, int n_in,
                              void* d_out, int out_size, void* d_ws, size_t ws_size,
                              hipStream_t stream) {
    const float* x  = (const float*)d_in[0];
    const float* wk = (const float*)d_in[1];
    const float* bk = (const float*)d_in[2];
    float* o = (float*)d_out;

    ushort_t* kern_ws = (ushort_t*)d_ws;
    ushort_t* xp8     = (ushort_t*)((char*)d_ws + XP8_OFF);
    unsigned* wbf     = (unsigned*)((char*)d_ws + WBF_OFF);

    cvt_xp8<<<dim3(65, 4, B_), dim3(256), 0, stream>>>(x, wk, xp8, wbf);
    kern_gemm<<<dim3(1024), dim3(256), 0, stream>>>(
        xp8, (const ushort_t*)wbf, bk, kern_ws);
    inv_apply<<<dim3(1024), dim3(256), 0, stream>>>(
        xp8, kern_ws, o);
}

// Round 13
// 105.032 us; speedup vs baseline: 1.0866x; 1.0866x over previous
//
#include <hip/hip_runtime.h>

// Involution2d, 2-kernel (R9 structure + depth-2 GEMM register pipeline).
// K0: x f32 [b][ch][px] -> xp8 bf16 [b][oct=ch/8][px][8ch] (16B per (oct,px)); w -> bf16.
//     xp8 serves BOTH the GEMM B-operand (fragment-shaped 16B reads) AND the
//     halo staging (pure b128 global->LDS copy, no conversion VALU).
// K1 per block (b, g, 4-row x 64-px tile):
//   GEMM (3-buffer reg pipeline, 2 chunks ahead, barrier-free):
//     kern[49 x 256px] = W_g @ x + bias -> kern2 LDS
//   halo batch0 staged BEFORE the single main barrier; batch1 prefetched into
//   registers during batch0 apply. 3 barriers total.
// LDS 39,872 B -> 4 blocks/CU.

#define B_   4
#define C_   256
#define G_   16
#define KK_  49
#define KS_  7
#define PD_  3

#define XP8_BYTES (B_*32*4096*8*2)       // 8,388,608
#define WBF_OFF   XP8_BYTES

#define SKW   28            // kern2 row stride, dwords (=56 bf16, 49 used)
#define HC_   70            // halo cols
#define HPOS  (10*HC_)      // 700 positions (10 rows x 70 cols)

typedef __attribute__((ext_vector_type(8))) short bf16x8;
typedef __attribute__((ext_vector_type(4))) float f32x4;
typedef unsigned short ushort_t;

__device__ inline unsigned f2bf(float f) {            // RNE fp32->bf16
    unsigned u = __float_as_uint(f);
    u += 0x7FFF + ((u >> 16) & 1);
    return u >> 16;
}

// ---------------- K0: x -> xp8 (channel-packed bf16); w -> bf16 ----------------
__global__ __launch_bounds__(256)
void cvt_xp8(const float* __restrict__ x, const float* __restrict__ wk,
             ushort_t* __restrict__ xp8, unsigned* __restrict__ wbf) {
    const int t = threadIdx.x;
    if (blockIdx.x == 64) {   // W convert: 100352 f32 pairs, 16 slices
        const int slice = blockIdx.z * 4 + blockIdx.y;
        const float2* wk2 = (const float2*)wk;
        const int base = slice * 6272;
        for (int k = t; k < 6272; k += 256) {
            float2 v = wk2[base + k];
            wbf[base + k] = f2bf(v.x) | (f2bf(v.y) << 16);
        }
        return;
    }
    __shared__ float tile[64][65];
    const int p0 = blockIdx.x * 64;
    const int c0 = blockIdx.y * 64;       // 8 octs per slice
    const int b  = blockIdx.z;
    const int px_r = t & 63;
    #pragma unroll
    for (int i = 0; i < 16; ++i) {
        int ch = (t >> 6) + i * 4;
        tile[ch][px_r] = x[((size_t)(b * C_ + c0 + ch) << 12) + p0 + px_r];
    }
    __syncthreads();
    const int px = t & 63;
    const int ob = t >> 6;                // 0..3
    #pragma unroll
    for (int jj = 0; jj < 2; ++jj) {
        const int j = ob + jj * 4;        // oct within slice, 0..7
        unsigned u[4];
        #pragma unroll
        for (int k2 = 0; k2 < 4; ++k2) {
            float a0 = tile[j * 8 + 2 * k2][px];
            float a1 = tile[j * 8 + 2 * k2 + 1][px];
            u[k2] = f2bf(a0) | (f2bf(a1) << 16);
        }
        ushort_t* dst = xp8 + (((size_t)((b << 5) + (c0 >> 3) + j) << 12) + p0 + px) * 8;
        *(uint4*)dst = make_uint4(u[0], u[1], u[2], u[3]);
    }
}

// halo position load: one b128 from xp8 (8 channels), zero-padded
__device__ inline uint4 stage_ld(const ushort_t* __restrict__ xp8,
                                 int b, int oct, int gy0, int e) {
    const int row = e / HC_;
    const int col = e - row * HC_;
    const int sy = gy0 + row - PD_;
    const int sx = col - PD_;
    if (sy >= 0 && sy < 64 && sx >= 0 && sx < 64)
        return *(const uint4*)(xp8 + (((size_t)((b << 5) + oct) << 12) + sy * 64 + sx) * 8);
    return make_uint4(0u, 0u, 0u, 0u);
}

// ---------------- K1: fused GEMM + apply ----------------
__global__ __launch_bounds__(256, 4)
void inv_fused(const ushort_t* __restrict__ xp8,
               const ushort_t* __restrict__ wbf,
               const float* __restrict__ bk,
               float* __restrict__ out) {
    __shared__ unsigned kern2[256 * SKW];     // 28,672 B  [pixel][28 dw]
    __shared__ unsigned halo4[HPOS * 4];      // 11,200 B  [pos][4dw = 8 ch bf16]

    const int bid  = blockIdx.x;
    const int g    = bid >> 6;                // same (b,tile) across g -> same XCD
    const int b    = (bid >> 4) & 3;
    const int tile = bid & 15;
    const int gy0  = tile * 4;
    const int p0   = tile * 256;

    const int tid  = threadIdx.x;
    const int wv   = tid >> 6;
    const int ln15 = tid & 15;
    const int quad = (tid & 63) >> 4;

    // ---- GEMM: wave wv owns n-cols p0+wv*64 (4 n-tiles) x 4 m-tiles ----
    f32x4 acc[16];
    #pragma unroll
    for (int i = 0; i < 16; ++i) acc[i] = (f32x4){0.f, 0.f, 0.f, 0.f};

    const ushort_t* ap[4];
    #pragma unroll
    for (int mt = 0; mt < 4; ++mt) {
        int r = mt * 16 + ln15; if (r > KK_ - 1) r = KK_ - 1;   // clamp pad rows
        ap[mt] = wbf + (size_t)(g * KK_ + r) * C_ + quad * 8;
    }
    // B: xp8 oct = cc/8 + quad; pixel = p0 + wv*64 + nt*16 + ln15
    const ushort_t* bp = xp8 + (((size_t)((b << 5) + quad) << 12) + p0 + wv * 64 + ln15) * 8;

    // 3-buffer register pipeline, 2 chunks in flight
    bf16x8 af[3][4], bf[3][4];
    #pragma unroll
    for (int kb = 0; kb < 2; ++kb) {
        const int cc = kb * 32;
        #pragma unroll
        for (int mt = 0; mt < 4; ++mt)
            af[kb][mt] = *(const bf16x8*)(ap[mt] + cc);
        #pragma unroll
        for (int nt = 0; nt < 4; ++nt)
            bf[kb][nt] = *(const bf16x8*)(bp + ((size_t)cc << 12) + nt * 128);
    }

    #pragma unroll
    for (int k = 0; k < 8; ++k) {
        const int cur = k % 3;
        if (k < 6) {
            const int nxt = (k + 2) % 3;
            const int cc  = (k + 2) * 32;
            #pragma unroll
            for (int mt = 0; mt < 4; ++mt)
                af[nxt][mt] = *(const bf16x8*)(ap[mt] + cc);
            #pragma unroll
            for (int nt = 0; nt < 4; ++nt)
                bf[nxt][nt] = *(const bf16x8*)(bp + ((size_t)cc << 12) + nt * 128);
        }
        #pragma unroll
        for (int mt = 0; mt < 4; ++mt) {
            #pragma unroll
            for (int nt = 0; nt < 4; ++nt) {
                acc[mt * 4 + nt] = __builtin_amdgcn_mfma_f32_16x16x32_bf16(
                    af[cur][mt], bf[cur][nt], acc[mt * 4 + nt], 0, 0, 0);
            }
        }
    }

    // ---- halo batch 0: pure b128 copy, before the main barrier ----
    for (int e = tid; e < HPOS; e += 256)
        *(uint4*)&halo4[e * 4] = stage_ld(xp8, b, 2 * g, gy0, e);

    // ---- epilogue: D[m=quad*4+r][n=ln15] -> kern2[pixel][m] bf16 ----
    #pragma unroll
    for (int mt = 0; mt < 3; ++mt) {                      // m <= 47
        const int m0 = mt * 16 + quad * 4;
        const float b0 = bk[g * KK_ + m0],     b1 = bk[g * KK_ + m0 + 1];
        const float b2 = bk[g * KK_ + m0 + 2], b3 = bk[g * KK_ + m0 + 3];
        #pragma unroll
        for (int nt = 0; nt < 4; ++nt) {
            const int p = wv * 64 + nt * 16 + ln15;
            uint2 d;
            d.x = f2bf(acc[mt * 4 + nt][0] + b0) | (f2bf(acc[mt * 4 + nt][1] + b1) << 16);
            d.y = f2bf(acc[mt * 4 + nt][2] + b2) | (f2bf(acc[mt * 4 + nt][3] + b3) << 16);
            *(uint2*)&kern2[p * SKW + mt * 8 + quad * 2] = d;
        }
    }
    if (quad == 0) {                                      // mt=3: only m=48 valid
        const float b48 = bk[g * KK_ + 48];
        #pragma unroll
        for (int nt = 0; nt < 4; ++nt) {
            const int p = wv * 64 + nt * 16 + ln15;
            kern2[p * SKW + 24] = f2bf(acc[12 + nt][0] + b48);   // lo=m48
        }
    }
    __syncthreads();   // barrier 1: kern2 + halo0 complete

    // ---- my pixel's 49 kern values: 7x ds_read_b128 + unpack ----
    float kv[KK_];
    {
        const uint4* kr = (const uint4*)&kern2[tid * SKW];
        unsigned kd[28];
        #pragma unroll
        for (int q = 0; q < 7; ++q) {
            uint4 h = kr[q];
            kd[4*q] = h.x; kd[4*q+1] = h.y; kd[4*q+2] = h.z; kd[4*q+3] = h.w;
        }
        #pragma unroll
        for (int k = 0; k < KK_; ++k) {
            unsigned d = kd[k >> 1];
            kv[k] = __uint_as_float((k & 1) ? (d & 0xffff0000u) : (d << 16));
        }
    }

    // ---- prefetch halo batch 1 into registers (in flight during apply0) ----
    uint4 pf0 = stage_ld(xp8, b, 2 * g + 1, gy0, tid);
    uint4 pf1 = stage_ld(xp8, b, 2 * g + 1, gy0, tid + 256);
    uint4 pf2 = (tid < HPOS - 512) ? stage_ld(xp8, b, 2 * g + 1, gy0, tid + 512)
                                   : make_uint4(0u, 0u, 0u, 0u);

    const int py = tid >> 6, px = tid & 63;

    #pragma unroll 1
    for (int hb = 0; hb < 2; ++hb) {
        if (hb) {
            __syncthreads();   // barrier 2: all done reading halo0
            *(uint4*)&halo4[tid * 4] = pf0;
            *(uint4*)&halo4[(tid + 256) * 4] = pf1;
            if (tid < HPOS - 512) *(uint4*)&halo4[(tid + 512) * 4] = pf2;
            __syncthreads();   // barrier 3: halo1 complete
        }
        float a[8];
        #pragma unroll
        for (int q = 0; q < 8; ++q) a[q] = 0.f;
        #pragma unroll
        for (int kh = 0; kh < KS_; ++kh) {
            const uint4* hr = (const uint4*)&halo4[((py + kh) * HC_ + px) * 4];
            #pragma unroll
            for (int kw = 0; kw < KS_; ++kw) {
                uint4 hv = hr[kw];
                float kk = kv[kh * KS_ + kw];
                a[0] = fmaf(__uint_as_float(hv.x << 16),          kk, a[0]);
                a[1] = fmaf(__uint_as_float(hv.x & 0xffff0000u),  kk, a[1]);
                a[2] = fmaf(__uint_as_float(hv.y << 16),          kk, a[2]);
                a[3] = fmaf(__uint_as_float(hv.y & 0xffff0000u),  kk, a[3]);
                a[4] = fmaf(__uint_as_float(hv.z << 16),          kk, a[4]);
                a[5] = fmaf(__uint_as_float(hv.z & 0xffff0000u),  kk, a[5]);
                a[6] = fmaf(__uint_as_float(hv.w << 16),          kk, a[6]);
                a[7] = fmaf(__uint_as_float(hv.w & 0xffff0000u),  kk, a[7]);
            }
        }
        const size_t o = ((size_t)(b * C_ + g * 16 + hb * 8) << 12) + p0 + tid;
        #pragma unroll
        for (int q = 0; q < 8; ++q)
            out[o + ((size_t)q << 12)] = a[q];
    }
}

extern "C" void kernel_launch(void* const* d_in, const int* in_sizes, int n_in,
                              void* d_out, int out_size, void* d_ws, size_t ws_size,
                              hipStream_t stream) {
    const float* x  = (const float*)d_in[0];
    const float* wk = (const float*)d_in[1];
    const float* bk = (const float*)d_in[2];
    float* o = (float*)d_out;

    ushort_t* xp8 = (ushort_t*)d_ws;
    unsigned* wbf = (unsigned*)((char*)d_ws + WBF_OFF);

    cvt_xp8<<<dim3(65, 4, B_), dim3(256), 0, stream>>>(x, wk, xp8, wbf);
    inv_fused<<<dim3(1024), dim3(256), 0, stream>>>(
        xp8, (const ushort_t*)wbf, bk, o);
}

// Round 14
// 103.366 us; speedup vs baseline: 1.1041x; 1.0161x over previous
//
#include <hip/hip_runtime.h>

// Involution2d, 2-kernel (R12 structure + mask-free hi-channel fma in apply).
// K0: x f32 [b][ch][px] -> xp8 bf16 [b][oct=ch/8][px][8ch]; w -> bf16.
// K1 per block (b, g, 4-row x 64-px tile):
//   GEMM (3-buffer reg pipeline, 2 chunks ahead, barrier-free) -> kern2 LDS
//   halo batch0 staged before the single main barrier; batch1 reg-prefetched.
//   apply: per halo dword, hi channel uses the dword directly as f32 (low 16
//   bits are sub-bf16 mantissa noise, <=0.4% rel) -> 12 VALU/tap instead of 16.
// LDS 39,872 B -> 4 blocks/CU.

#define B_   4
#define C_   256
#define G_   16
#define KK_  49
#define KS_  7
#define PD_  3

#define XP8_BYTES (B_*32*4096*8*2)       // 8,388,608
#define WBF_OFF   XP8_BYTES

#define SKW   28            // kern2 row stride, dwords (=56 bf16, 49 used)
#define HC_   70            // halo cols
#define HPOS  (10*HC_)      // 700 positions (10 rows x 70 cols)

typedef __attribute__((ext_vector_type(8))) short bf16x8;
typedef __attribute__((ext_vector_type(4))) float f32x4;
typedef unsigned short ushort_t;

__device__ inline unsigned f2bf(float f) {            // RNE fp32->bf16
    unsigned u = __float_as_uint(f);
    u += 0x7FFF + ((u >> 16) & 1);
    return u >> 16;
}

// ---------------- K0: x -> xp8 (channel-packed bf16); w -> bf16 ----------------
__global__ __launch_bounds__(256)
void cvt_xp8(const float* __restrict__ x, const float* __restrict__ wk,
             ushort_t* __restrict__ xp8, unsigned* __restrict__ wbf) {
    const int t = threadIdx.x;
    if (blockIdx.x == 64) {   // W convert: 100352 f32 pairs, 16 slices
        const int slice = blockIdx.z * 4 + blockIdx.y;
        const float2* wk2 = (const float2*)wk;
        const int base = slice * 6272;
        for (int k = t; k < 6272; k += 256) {
            float2 v = wk2[base + k];
            wbf[base + k] = f2bf(v.x) | (f2bf(v.y) << 16);
        }
        return;
    }
    __shared__ float tile[64][65];
    const int p0 = blockIdx.x * 64;
    const int c0 = blockIdx.y * 64;       // 8 octs per slice
    const int b  = blockIdx.z;
    const int px_r = t & 63;
    #pragma unroll
    for (int i = 0; i < 16; ++i) {
        int ch = (t >> 6) + i * 4;
        tile[ch][px_r] = x[((size_t)(b * C_ + c0 + ch) << 12) + p0 + px_r];
    }
    __syncthreads();
    const int px = t & 63;
    const int ob = t >> 6;                // 0..3
    #pragma unroll
    for (int jj = 0; jj < 2; ++jj) {
        const int j = ob + jj * 4;        // oct within slice, 0..7
        unsigned u[4];
        #pragma unroll
        for (int k2 = 0; k2 < 4; ++k2) {
            float a0 = tile[j * 8 + 2 * k2][px];
            float a1 = tile[j * 8 + 2 * k2 + 1][px];
            u[k2] = f2bf(a0) | (f2bf(a1) << 16);
        }
        ushort_t* dst = xp8 + (((size_t)((b << 5) + (c0 >> 3) + j) << 12) + p0 + px) * 8;
        *(uint4*)dst = make_uint4(u[0], u[1], u[2], u[3]);
    }
}

// halo position load: one b128 from xp8 (8 channels), zero-padded
__device__ inline uint4 stage_ld(const ushort_t* __restrict__ xp8,
                                 int b, int oct, int gy0, int e) {
    const int row = e / HC_;
    const int col = e - row * HC_;
    const int sy = gy0 + row - PD_;
    const int sx = col - PD_;
    if (sy >= 0 && sy < 64 && sx >= 0 && sx < 64)
        return *(const uint4*)(xp8 + (((size_t)((b << 5) + oct) << 12) + sy * 64 + sx) * 8);
    return make_uint4(0u, 0u, 0u, 0u);
}

// ---------------- K1: fused GEMM + apply ----------------
__global__ __launch_bounds__(256, 4)
void inv_fused(const ushort_t* __restrict__ xp8,
               const ushort_t* __restrict__ wbf,
               const float* __restrict__ bk,
               float* __restrict__ out) {
    __shared__ unsigned kern2[256 * SKW];     // 28,672 B  [pixel][28 dw]
    __shared__ unsigned halo4[HPOS * 4];      // 11,200 B  [pos][4dw = 8 ch bf16]

    const int bid  = blockIdx.x;
    const int g    = bid >> 6;                // same (b,tile) across g -> same XCD
    const int b    = (bid >> 4) & 3;
    const int tile = bid & 15;
    const int gy0  = tile * 4;
    const int p0   = tile * 256;

    const int tid  = threadIdx.x;
    const int wv   = tid >> 6;
    const int ln15 = tid & 15;
    const int quad = (tid & 63) >> 4;

    // ---- GEMM: wave wv owns n-cols p0+wv*64 (4 n-tiles) x 4 m-tiles ----
    f32x4 acc[16];
    #pragma unroll
    for (int i = 0; i < 16; ++i) acc[i] = (f32x4){0.f, 0.f, 0.f, 0.f};

    const ushort_t* ap[4];
    #pragma unroll
    for (int mt = 0; mt < 4; ++mt) {
        int r = mt * 16 + ln15; if (r > KK_ - 1) r = KK_ - 1;   // clamp pad rows
        ap[mt] = wbf + (size_t)(g * KK_ + r) * C_ + quad * 8;
    }
    const ushort_t* bp = xp8 + (((size_t)((b << 5) + quad) << 12) + p0 + wv * 64 + ln15) * 8;

    // 3-buffer register pipeline, 2 chunks in flight
    bf16x8 af[3][4], bf[3][4];
    #pragma unroll
    for (int kb = 0; kb < 2; ++kb) {
        const int cc = kb * 32;
        #pragma unroll
        for (int mt = 0; mt < 4; ++mt)
            af[kb][mt] = *(const bf16x8*)(ap[mt] + cc);
        #pragma unroll
        for (int nt = 0; nt < 4; ++nt)
            bf[kb][nt] = *(const bf16x8*)(bp + ((size_t)cc << 12) + nt * 128);
    }

    #pragma unroll
    for (int k = 0; k < 8; ++k) {
        const int cur = k % 3;
        if (k < 6) {
            const int nxt = (k + 2) % 3;
            const int cc  = (k + 2) * 32;
            #pragma unroll
            for (int mt = 0; mt < 4; ++mt)
                af[nxt][mt] = *(const bf16x8*)(ap[mt] + cc);
            #pragma unroll
            for (int nt = 0; nt < 4; ++nt)
                bf[nxt][nt] = *(const bf16x8*)(bp + ((size_t)cc << 12) + nt * 128);
        }
        #pragma unroll
        for (int mt = 0; mt < 4; ++mt) {
            #pragma unroll
            for (int nt = 0; nt < 4; ++nt) {
                acc[mt * 4 + nt] = __builtin_amdgcn_mfma_f32_16x16x32_bf16(
                    af[cur][mt], bf[cur][nt], acc[mt * 4 + nt], 0, 0, 0);
            }
        }
    }

    // ---- halo batch 0: pure b128 copy, before the main barrier ----
    for (int e = tid; e < HPOS; e += 256)
        *(uint4*)&halo4[e * 4] = stage_ld(xp8, b, 2 * g, gy0, e);

    // ---- epilogue: D[m=quad*4+r][n=ln15] -> kern2[pixel][m] bf16 ----
    #pragma unroll
    for (int mt = 0; mt < 3; ++mt) {                      // m <= 47
        const int m0 = mt * 16 + quad * 4;
        const float b0 = bk[g * KK_ + m0],     b1 = bk[g * KK_ + m0 + 1];
        const float b2 = bk[g * KK_ + m0 + 2], b3 = bk[g * KK_ + m0 + 3];
        #pragma unroll
        for (int nt = 0; nt < 4; ++nt) {
            const int p = wv * 64 + nt * 16 + ln15;
            uint2 d;
            d.x = f2bf(acc[mt * 4 + nt][0] + b0) | (f2bf(acc[mt * 4 + nt][1] + b1) << 16);
            d.y = f2bf(acc[mt * 4 + nt][2] + b2) | (f2bf(acc[mt * 4 + nt][3] + b3) << 16);
            *(uint2*)&kern2[p * SKW + mt * 8 + quad * 2] = d;
        }
    }
    if (quad == 0) {                                      // mt=3: only m=48 valid
        const float b48 = bk[g * KK_ + 48];
        #pragma unroll
        for (int nt = 0; nt < 4; ++nt) {
            const int p = wv * 64 + nt * 16 + ln15;
            kern2[p * SKW + 24] = f2bf(acc[12 + nt][0] + b48);   // lo=m48
        }
    }
    __syncthreads();   // barrier 1: kern2 + halo0 complete

    // ---- my pixel's 49 kern values: 7x ds_read_b128 + unpack ----
    float kv[KK_];
    {
        const uint4* kr = (const uint4*)&kern2[tid * SKW];
        unsigned kd[28];
        #pragma unroll
        for (int q = 0; q < 7; ++q) {
            uint4 h = kr[q];
            kd[4*q] = h.x; kd[4*q+1] = h.y; kd[4*q+2] = h.z; kd[4*q+3] = h.w;
        }
        #pragma unroll
        for (int k = 0; k < KK_; ++k) {
            unsigned d = kd[k >> 1];
            kv[k] = __uint_as_float((k & 1) ? (d & 0xffff0000u) : (d << 16));
        }
    }

    // ---- prefetch halo batch 1 into registers (in flight during apply0) ----
    uint4 pf0 = stage_ld(xp8, b, 2 * g + 1, gy0, tid);
    uint4 pf1 = stage_ld(xp8, b, 2 * g + 1, gy0, tid + 256);
    uint4 pf2 = (tid < HPOS - 512) ? stage_ld(xp8, b, 2 * g + 1, gy0, tid + 512)
                                   : make_uint4(0u, 0u, 0u, 0u);

    const int py = tid >> 6, px = tid & 63;

    #pragma unroll 1
    for (int hb = 0; hb < 2; ++hb) {
        if (hb) {
            __syncthreads();   // barrier 2: all done reading halo0
            *(uint4*)&halo4[tid * 4] = pf0;
            *(uint4*)&halo4[(tid + 256) * 4] = pf1;
            if (tid < HPOS - 512) *(uint4*)&halo4[(tid + 512) * 4] = pf2;
            __syncthreads();   // barrier 3: halo1 complete
        }
        float a[8];
        #pragma unroll
        for (int q = 0; q < 8; ++q) a[q] = 0.f;
        #pragma unroll
        for (int kh = 0; kh < KS_; ++kh) {
            const uint4* hr = (const uint4*)&halo4[((py + kh) * HC_ + px) * 4];
            #pragma unroll
            for (int kw = 0; kw < KS_; ++kw) {
                uint4 hv = hr[kw];
                float kk = kv[kh * KS_ + kw];
                // hi channel uses the raw dword as f32: low 16 bits are
                // sub-bf16 mantissa noise (<=0.4% rel), threshold is 2%.
                a[0] = fmaf(__uint_as_float(hv.x << 16), kk, a[0]);
                a[1] = fmaf(__uint_as_float(hv.x),       kk, a[1]);
                a[2] = fmaf(__uint_as_float(hv.y << 16), kk, a[2]);
                a[3] = fmaf(__uint_as_float(hv.y),       kk, a[3]);
                a[4] = fmaf(__uint_as_float(hv.z << 16), kk, a[4]);
                a[5] = fmaf(__uint_as_float(hv.z),       kk, a[5]);
                a[6] = fmaf(__uint_as_float(hv.w << 16), kk, a[6]);
                a[7] = fmaf(__uint_as_float(hv.w),       kk, a[7]);
            }
        }
        const size_t o = ((size_t)(b * C_ + g * 16 + hb * 8) << 12) + p0 + tid;
        #pragma unroll
        for (int q = 0; q < 8; ++q)
            out[o + ((size_t)q << 12)] = a[q];
    }
}

extern "C" void kernel_launch(void* const* d_in, const int* in_sizes, int n_in,
                              void* d_out, int out_size, void* d_ws, size_t ws_size,
                              hipStream_t stream) {
    const float* x  = (const float*)d_in[0];
    const float* wk = (const float*)d_in[1];
    const float* bk = (const float*)d_in[2];
    float* o = (float*)d_out;

    ushort_t* xp8 = (ushort_t*)d_ws;
    unsigned* wbf = (unsigned*)((char*)d_ws + WBF_OFF);

    cvt_xp8<<<dim3(65, 4, B_), dim3(256), 0, stream>>>(x, wk, xp8, wbf);
    inv_fused<<<dim3(1024), dim3(256), 0, stream>>>(
        xp8, (const ushort_t*)wbf, bk, o);
}